// Round 1
// baseline (269.983 us; speedup 1.0000x reference)
//
#include <hip/hip_runtime.h>
#include <stdint.h>

#define B_ 4
#define N_ 16384
#define M_ 4096
#define C_ 64
#define S_ 32
#define R2_ 0.16f   // float(0.4*0.4) == float(0.16000000000000003)

// ---- workspace layout (total ~19.9 MB) ----
// xyz4: [B][N] float4 {x,y,z,pp}      @ 0        (1 MB)
// ft:   [B][N][C] float (transposed)  @ 1 MB     (16 MB)
// idx:  [B][M][S] int                 @ 17.8 MB  (2 MB)
static const size_t OFF_XYZ4 = 0;
static const size_t OFF_FT   = (size_t)B_ * N_ * 4 * sizeof(float);
static const size_t OFF_IDX  = OFF_FT + (size_t)B_ * N_ * C_ * sizeof(float);

// A1: pack xyz into float4 with pp = (x*x + y*y) + z*z, per-op rounded (match XLA reduce)
__global__ __launch_bounds__(256) void pack_xyz4(const float* __restrict__ xyz,
                                                 float4* __restrict__ xyz4) {
    int i = blockIdx.x * 256 + threadIdx.x;       // [0, B*N)
    float x = xyz[3 * i + 0];
    float y = xyz[3 * i + 1];
    float z = xyz[3 * i + 2];
    float pp = __fadd_rn(__fadd_rn(__fmul_rn(x, x), __fmul_rn(y, y)), __fmul_rn(z, z));
    xyz4[i] = make_float4(x, y, z, pp);
}

// A2: transpose features (B,C,N) -> (B,N,C)
__global__ __launch_bounds__(256) void transpose_feat(const float* __restrict__ f,
                                                      float* __restrict__ ft) {
    __shared__ float tile[64][65];
    int b  = blockIdx.x >> 8;           // 256 blocks per batch
    int n0 = (blockIdx.x & 255) << 6;   // 64-wide n tile
    int tid  = threadIdx.x;
    int lane = tid & 63;
    int grp  = tid >> 6;                // 0..3
    #pragma unroll
    for (int r = 0; r < 16; ++r) {
        int c = r * 4 + grp;
        tile[c][lane] = f[((size_t)b * C_ + c) * N_ + n0 + lane];
    }
    __syncthreads();
    #pragma unroll
    for (int r = 0; r < 16; ++r) {
        int nl = r * 4 + grp;
        ft[((size_t)b * N_ + n0 + nl) * C_ + lane] = tile[lane][nl];
    }
}

// B: ball query, one wave (64 lanes) per query. 256-thread block = 4 queries,
// shares LDS-staged xyz chunks. Exact first-32-by-index semantics with early exit.
__global__ __launch_bounds__(256) void ball_query(const float4* __restrict__ xyz4,
                                                  const float* __restrict__ newxyz,
                                                  int* __restrict__ idx) {
    __shared__ float4 pts[1024];
    int tid  = threadIdx.x;
    int lane = tid & 63;
    int w    = tid >> 6;
    int b    = blockIdx.x >> 10;                    // 1024 blocks per batch
    int m    = ((blockIdx.x & 1023) << 2) + w;      // 4 queries per block
    size_t qb = ((size_t)b * M_ + m) * 3;
    float qx = newxyz[qb + 0];
    float qy = newxyz[qb + 1];
    float qz = newxyz[qb + 2];
    float qq = __fadd_rn(__fadd_rn(__fmul_rn(qx, qx), __fmul_rn(qy, qy)), __fmul_rn(qz, qz));

    const float4* xb = xyz4 + (size_t)b * N_;
    int* outp = idx + ((size_t)b * M_ + m) * S_;

    int count = 0;
    int first = 0;
    bool done = false;

    for (int ch = 0; ch < N_ / 1024; ++ch) {
        int base = ch * 1024;
        // cooperative stage (previous scan separated by __syncthreads_and barrier)
        #pragma unroll
        for (int k = 0; k < 4; ++k) pts[tid + 256 * k] = xb[base + tid + 256 * k];
        __syncthreads();
        if (!done) {
            for (int it = 0; it < 16; ++it) {
                float4 P = pts[it * 64 + lane];
                // dot: Eigen-gemm style FMA chain, k = x,y,z; first product exactly rounded
                float dot = __fmaf_rn(qz, P.z, __fmaf_rn(qy, P.y, __fmul_rn(qx, P.x)));
                float d2  = __fsub_rn(__fadd_rn(qq, P.w), __fmul_rn(2.0f, dot));
                bool inb = d2 < R2_;
                unsigned long long mask = __ballot(inb);
                if (mask) {
                    int pc        = __popcll(mask);
                    int remaining = 32 - count;
                    if (count == 0) first = base + it * 64 + (int)__builtin_ctzll(mask);
                    int rank = __popcll(mask & ((1ull << lane) - 1ull));
                    if (inb && rank < remaining) outp[count + rank] = base + it * 64 + lane;
                    count += (pc < remaining ? pc : remaining);
                    if (count >= 32) { done = true; break; }
                }
            }
        }
        if (__syncthreads_and((int)done)) break;
    }
    // pad remaining slots with first-found index (0 if none)
    if (count < 32) {
        for (int s = count + lane; s < 32; s += 64) outp[s] = first;
    }
}

// C: gather + assemble output (B, 67, M, S). One block per (b,m).
__global__ __launch_bounds__(256) void group_out(const float4* __restrict__ xyz4,
                                                 const float* __restrict__ ft,
                                                 const float* __restrict__ newxyz,
                                                 const int* __restrict__ idx,
                                                 float* __restrict__ out) {
    __shared__ int   sidx[32];
    __shared__ float q[3];
    int tid = threadIdx.x;
    int b   = blockIdx.x >> 12;     // 4096 blocks per batch
    int m   = blockIdx.x & 4095;
    if (tid < 32) sidx[tid] = idx[((size_t)b * M_ + m) * S_ + tid];
    if (tid < 3)  q[tid]    = newxyz[((size_t)b * M_ + m) * 3 + tid];
    __syncthreads();

    int s  = tid & 31;
    int c8 = tid >> 5;              // 0..7 -> channels c8*8 .. c8*8+7
    int p  = sidx[s];

    const float* fp = ft + ((size_t)b * N_ + p) * C_ + c8 * 8;
    float4 v0 = *(const float4*)(fp);
    float4 v1 = *(const float4*)(fp + 4);

    const size_t st = (size_t)M_ * S_;  // stride between channel rows
    size_t ob = (((size_t)b * 67 + 3 + c8 * 8) * M_ + m) * S_ + s;
    out[ob + 0 * st] = v0.x;
    out[ob + 1 * st] = v0.y;
    out[ob + 2 * st] = v0.z;
    out[ob + 3 * st] = v0.w;
    out[ob + 4 * st] = v1.x;
    out[ob + 5 * st] = v1.y;
    out[ob + 6 * st] = v1.z;
    out[ob + 7 * st] = v1.w;

    if (tid < 32) {
        float4 P = xyz4[(size_t)b * N_ + p];
        size_t xb = (((size_t)b * 67 + 0) * M_ + m) * S_ + s;
        out[xb + 0 * st] = P.x - q[0];
        out[xb + 1 * st] = P.y - q[1];
        out[xb + 2 * st] = P.z - q[2];
    }
}

extern "C" void kernel_launch(void* const* d_in, const int* in_sizes, int n_in,
                              void* d_out, int out_size, void* d_ws, size_t ws_size,
                              hipStream_t stream) {
    const float* xyz    = (const float*)d_in[0];   // (B, N, 3)
    const float* newxyz = (const float*)d_in[1];   // (B, M, 3)
    const float* feat   = (const float*)d_in[2];   // (B, C, N)
    float* out = (float*)d_out;                    // (B, 67, M, S)

    char* ws = (char*)d_ws;
    float4* xyz4 = (float4*)(ws + OFF_XYZ4);
    float*  ft   = (float*)(ws + OFF_FT);
    int*    idxb = (int*)(ws + OFF_IDX);

    pack_xyz4<<<(B_ * N_) / 256, 256, 0, stream>>>(xyz, xyz4);
    transpose_feat<<<B_ * (N_ / 64), 256, 0, stream>>>(feat, ft);
    ball_query<<<(B_ * M_) / 4, 256, 0, stream>>>(xyz4, newxyz, idxb);
    group_out<<<B_ * M_, 256, 0, stream>>>(xyz4, ft, newxyz, idxb, out);
}

// Round 3
// 230.404 us; speedup vs baseline: 1.1718x; 1.1718x over previous
//
#include <hip/hip_runtime.h>
#include <stdint.h>

#define B_ 4
#define N_ 16384
#define M_ 4096
#define C_ 64
#define S_ 32
#define R2_ 0.16f   // float(0.4*0.4)

// ---- workspace layout (total ~19.9 MB) ----
// xyz4: [B][N] float4 {x,y,z,pp}      @ 0        (1 MB)
// ft:   [B][N][C] float (transposed)  @ 1 MB     (16 MB)
// idx:  [B][M][S] int                 @ 17.8 MB  (2 MB)
static const size_t OFF_XYZ4 = 0;
static const size_t OFF_FT   = (size_t)B_ * N_ * 4 * sizeof(float);
static const size_t OFF_IDX  = OFF_FT + (size_t)B_ * N_ * C_ * sizeof(float);

// A1: pack xyz into float4 with pp = (x*x + y*y) + z*z, per-op rounded (bit-exact vs ref)
__global__ __launch_bounds__(256) void pack_xyz4(const float* __restrict__ xyz,
                                                 float4* __restrict__ xyz4) {
    int i = blockIdx.x * 256 + threadIdx.x;       // [0, B*N)
    float x = xyz[3 * i + 0];
    float y = xyz[3 * i + 1];
    float z = xyz[3 * i + 2];
    float pp = __fadd_rn(__fadd_rn(__fmul_rn(x, x), __fmul_rn(y, y)), __fmul_rn(z, z));
    xyz4[i] = make_float4(x, y, z, pp);
}

// A2: transpose features (B,C,N) -> (B,N,C)
__global__ __launch_bounds__(256) void transpose_feat(const float* __restrict__ f,
                                                      float* __restrict__ ft) {
    __shared__ float tile[64][65];
    int b  = blockIdx.x >> 8;           // 256 blocks per batch
    int n0 = (blockIdx.x & 255) << 6;   // 64-wide n tile
    int tid  = threadIdx.x;
    int lane = tid & 63;
    int grp  = tid >> 6;                // 0..3
    #pragma unroll
    for (int r = 0; r < 16; ++r) {
        int c = r * 4 + grp;
        tile[c][lane] = f[((size_t)b * C_ + c) * N_ + n0 + lane];
    }
    __syncthreads();
    #pragma unroll
    for (int r = 0; r < 16; ++r) {
        int nl = r * 4 + grp;
        ft[((size_t)b * N_ + n0 + nl) * C_ + lane] = tile[lane][nl];
    }
}

// B: ball query — one wave owns 4 queries, no LDS, no barriers.
// Each lane loads points (coalesced float4, L2-resident), reused across the
// wave's 4 queries. Done queries skip compute (uniform branch); wave exits
// when all 4 done. 128 points in flight via prefetch.
__global__ __launch_bounds__(256) void ball_query(const float4* __restrict__ xyz4,
                                                  const float* __restrict__ newxyz,
                                                  int* __restrict__ idx) {
    int tid  = threadIdx.x;
    int lane = tid & 63;
    int gw   = (blockIdx.x << 2) + (tid >> 6);   // global wave id, 0..4095
    int b    = gw >> 10;                          // 1024 waves per batch
    int m0   = (gw & 1023) << 2;                  // first of this wave's 4 queries

    float qx[4], qy[4], qz[4], qq[4];
    int*  outp[4];
    #pragma unroll
    for (int q = 0; q < 4; ++q) {
        size_t qb = ((size_t)b * M_ + m0 + q) * 3;
        float x = newxyz[qb + 0], y = newxyz[qb + 1], z = newxyz[qb + 2];
        qx[q] = x; qy[q] = y; qz[q] = z;
        qq[q] = __fadd_rn(__fadd_rn(__fmul_rn(x, x), __fmul_rn(y, y)), __fmul_rn(z, z));
        outp[q] = idx + ((size_t)b * M_ + m0 + q) * S_;
    }

    int count[4] = {0, 0, 0, 0};
    int first[4] = {0, 0, 0, 0};
    int done = 0;
    const float4* xb = xyz4 + (size_t)b * N_;
    unsigned long long lmlt = (1ull << lane) - 1ull;

    float4 P0 = xb[lane];
    float4 P1 = xb[64 + lane];

    for (int base = 0; base < N_; base += 128) {
        float4 Npre0 = P0, Npre1 = P1;
        if (base + 128 < N_) {
            Npre0 = xb[base + 128 + lane];
            Npre1 = xb[base + 192 + lane];
        }
        #pragma unroll
        for (int q = 0; q < 4; ++q) {
            if (done & (1 << q)) continue;
            // sub-block 0: points base .. base+63  (bit-exact distance chain)
            {
                float dot = __fmaf_rn(qz[q], P0.z, __fmaf_rn(qy[q], P0.y, __fmul_rn(qx[q], P0.x)));
                float d2  = __fsub_rn(__fadd_rn(qq[q], P0.w), __fmul_rn(2.0f, dot));
                bool inb = d2 < R2_;
                unsigned long long mk = __ballot(inb);
                if (mk) {
                    int pc  = __popcll(mk);
                    int rem = 32 - count[q];
                    if (count[q] == 0) first[q] = base + (int)__builtin_ctzll(mk);
                    int rank = __popcll(mk & lmlt);
                    if (inb && rank < rem) outp[q][count[q] + rank] = base + lane;
                    count[q] += (pc < rem ? pc : rem);
                    if (count[q] >= 32) { done |= (1 << q); continue; }
                }
            }
            // sub-block 1: points base+64 .. base+127
            {
                float dot = __fmaf_rn(qz[q], P1.z, __fmaf_rn(qy[q], P1.y, __fmul_rn(qx[q], P1.x)));
                float d2  = __fsub_rn(__fadd_rn(qq[q], P1.w), __fmul_rn(2.0f, dot));
                bool inb = d2 < R2_;
                unsigned long long mk = __ballot(inb);
                if (mk) {
                    int pc  = __popcll(mk);
                    int rem = 32 - count[q];
                    if (count[q] == 0) first[q] = base + 64 + (int)__builtin_ctzll(mk);
                    int rank = __popcll(mk & lmlt);
                    if (inb && rank < rem) outp[q][count[q] + rank] = base + 64 + lane;
                    count[q] += (pc < rem ? pc : rem);
                    if (count[q] >= 32) { done |= (1 << q); }
                }
            }
        }
        if (done == 15) break;
        P0 = Npre0;
        P1 = Npre1;
    }

    // pad remaining slots with first-found index (0 if none)
    #pragma unroll
    for (int q = 0; q < 4; ++q) {
        if (count[q] < 32) {
            for (int s = count[q] + lane; s < 32; s += 64) outp[q][s] = first[q];
        }
    }
}

// C: gather + assemble output (B, 67, M, S). One block per (b,m).
__global__ __launch_bounds__(256) void group_out(const float4* __restrict__ xyz4,
                                                 const float* __restrict__ ft,
                                                 const float* __restrict__ newxyz,
                                                 const int* __restrict__ idx,
                                                 float* __restrict__ out) {
    __shared__ int   sidx[32];
    __shared__ float q[3];
    int tid = threadIdx.x;
    int b   = blockIdx.x >> 12;     // 4096 blocks per batch
    int m   = blockIdx.x & 4095;
    if (tid < 32) sidx[tid] = idx[((size_t)b * M_ + m) * S_ + tid];
    if (tid < 3)  q[tid]    = newxyz[((size_t)b * M_ + m) * 3 + tid];
    __syncthreads();

    int s  = tid & 31;
    int c8 = tid >> 5;              // 0..7 -> channels c8*8 .. c8*8+7
    int p  = sidx[s];

    const float* fp = ft + ((size_t)b * N_ + p) * C_ + c8 * 8;
    float4 v0 = *(const float4*)(fp);
    float4 v1 = *(const float4*)(fp + 4);

    const size_t st = (size_t)M_ * S_;  // stride between channel rows
    size_t ob = (((size_t)b * 67 + 3 + c8 * 8) * M_ + m) * S_ + s;
    out[ob + 0 * st] = v0.x;
    out[ob + 1 * st] = v0.y;
    out[ob + 2 * st] = v0.z;
    out[ob + 3 * st] = v0.w;
    out[ob + 4 * st] = v1.x;
    out[ob + 5 * st] = v1.y;
    out[ob + 6 * st] = v1.z;
    out[ob + 7 * st] = v1.w;

    if (tid < 32) {
        float4 P = xyz4[(size_t)b * N_ + p];
        size_t xb = (((size_t)b * 67 + 0) * M_ + m) * S_ + s;
        out[xb + 0 * st] = P.x - q[0];
        out[xb + 1 * st] = P.y - q[1];
        out[xb + 2 * st] = P.z - q[2];
    }
}

extern "C" void kernel_launch(void* const* d_in, const int* in_sizes, int n_in,
                              void* d_out, int out_size, void* d_ws, size_t ws_size,
                              hipStream_t stream) {
    const float* xyz    = (const float*)d_in[0];   // (B, N, 3)
    const float* newxyz = (const float*)d_in[1];   // (B, M, 3)
    const float* feat   = (const float*)d_in[2];   // (B, C, N)
    float* out = (float*)d_out;                    // (B, 67, M, S)

    char* ws = (char*)d_ws;
    float4* xyz4 = (float4*)(ws + OFF_XYZ4);
    float*  ft   = (float*)(ws + OFF_FT);
    int*    idxb = (int*)(ws + OFF_IDX);

    pack_xyz4<<<(B_ * N_) / 256, 256, 0, stream>>>(xyz, xyz4);
    transpose_feat<<<B_ * (N_ / 64), 256, 0, stream>>>(feat, ft);
    ball_query<<<(B_ * M_) / 16, 256, 0, stream>>>(xyz4, newxyz, idxb);
    group_out<<<B_ * M_, 256, 0, stream>>>(xyz4, ft, newxyz, idxb, out);
}